// Round 3
// baseline (363.042 us; speedup 1.0000x reference)
//
#include <hip/hip_runtime.h>
#include <hip/hip_bf16.h>
#include <stdint.h>
#include <stddef.h>

typedef __attribute__((ext_vector_type(8))) short short8;
typedef __attribute__((ext_vector_type(4))) float floatx4;

#define AS_GLOBAL(p) (const __attribute__((address_space(1))) void*)(p)
#define AS_LDS(p)    (__attribute__((address_space(3))) void*)(p)

static constexpr int IN_DIM  = 4096;
static constexpr int OUT_DIM = 4096;
static constexpr int S_DIM   = 256;
static constexpr int S2      = 512;   // both branches concatenated along rank

// ---------------- prep: W1, W2 only (x-conversion fused into gemm1) --------
// blocks [0, 2048):    W1[s,i] = v2[i] * sign(V[s,i])           (4 elem/thread)
// blocks [2048, 4096): W2[o,s] = u1[o]*v1[s]*u2[s]*sign(U[o,s]) (4 elem/thread)
// Traffic: ~21 MB total -> ~4 us (was 222 MB with the x->bf16 pass).
__global__ void prep_kernel(const float* __restrict__ V, const float* __restrict__ v2,
                            const float* __restrict__ V_R, const float* __restrict__ v2_R,
                            const float* __restrict__ U, const float* __restrict__ u1,
                            const float* __restrict__ v1, const float* __restrict__ u2,
                            const float* __restrict__ U_R, const float* __restrict__ u1_R,
                            const float* __restrict__ v1_R, const float* __restrict__ u2_R,
                            __hip_bfloat16* __restrict__ W1,
                            __hip_bfloat16* __restrict__ W2) {
  const int bid = blockIdx.x;
  if (bid < 2048) {
    const int idx4 = (bid * 256 + threadIdx.x) * 4;   // over S2*IN_DIM
    const int i = idx4 & (IN_DIM - 1);
    const int s = idx4 >> 12;
    floatx4 w, sc;
    if (s < S_DIM) {
      w  = *(const floatx4*)(V + s * IN_DIM + i);
      sc = *(const floatx4*)(v2 + i);
    } else {
      w  = *(const floatx4*)(V_R + (s - S_DIM) * IN_DIM + i);
      sc = *(const floatx4*)(v2_R + i);
    }
    union { ushort4 v; __hip_bfloat16 h[4]; } u;
#pragma unroll
    for (int j = 0; j < 4; ++j) {
      const float sg = (w[j] > 0.f) ? 1.f : ((w[j] < 0.f) ? -1.f : 0.f);
      u.h[j] = __float2bfloat16(sg * sc[j]);
    }
    *(ushort4*)((unsigned short*)W1 + idx4) = u.v;
  } else {
    const int idx4 = ((bid - 2048) * 256 + threadIdx.x) * 4;   // over OUT_DIM*S2
    const int s = idx4 & (S2 - 1);
    const int o = idx4 >> 9;
    floatx4 w, scs;
    float sco;
    if (s < S_DIM) {
      w   = *(const floatx4*)(U + o * S_DIM + s);
      sco = u1[o];
      const floatx4 a = *(const floatx4*)(v1 + s);
      const floatx4 b = *(const floatx4*)(u2 + s);
      scs = a * b;
    } else {
      const int ss = s - S_DIM;
      w   = *(const floatx4*)(U_R + o * S_DIM + ss);
      sco = u1_R[o];
      const floatx4 a = *(const floatx4*)(v1_R + ss);
      const floatx4 b = *(const floatx4*)(u2_R + ss);
      scs = a * b;
    }
    union { ushort4 v; __hip_bfloat16 h[4]; } u;
#pragma unroll
    for (int j = 0; j < 4; ++j) {
      const float sg = (w[j] > 0.f) ? 1.f : ((w[j] < 0.f) ? -1.f : 0.f);
      u.h[j] = __float2bfloat16(sg * sco * scs[j]);
    }
    *(ushort4*)((unsigned short*)W2 + idx4) = u.v;
  }
}

// ---------------- GEMM1: H[M,512] = fp32 X[M,4096] @ W1[512,4096]^T -------
// ROUND-0 structure (known-good 345us config): BM=128, BN=64, BK=64, 256thr,
// 64x32 wave tiles (acc[4][2]), dbuf, 2 blocks/CU = 8 waves/CU. The round-1
// 64x64-wave reshape gave 1 wave/SIMD (only 1024 waves exist at that tile) —
// latency-hiding loss beat the LDS-BW win. Reverted.
// NEW: A is read DIRECTLY from fp32 x and converted in the staging path
// (global_load_dwordx4 -> cvt -> ds_write_b128 into the same XOR-chunk
// layout). Eliminates prep's 192 MB Xb round-trip. A loads issue pre-MFMA,
// convert post-MFMA (latency hidden under compute, T14 pattern); single
// barrier per K-step preserved (writes go to buf^1, reads from buf).
__global__ __launch_bounds__(256, 2)
void gemm1_kernel(const float* __restrict__ X,
                  const __hip_bfloat16* __restrict__ B,
                  __hip_bfloat16* __restrict__ C) {
  constexpr int K = IN_DIM;   // 4096
  constexpr int N = S2;       // 512
  constexpr int BM = 128, BN = 64, BK = 64;

  __shared__ __hip_bfloat16 As[2][BM * BK];   // 2 x 16 KB
  __shared__ __hip_bfloat16 Bs[2][BN * BK];   // 2 x 8 KB

  const int t = threadIdx.x;
  const int wave = t >> 6;
  const int lane = t & 63;
  const int r16 = lane & 15;
  const int quad = lane >> 4;

  // XCD swizzle: 512 blocks; XCD c handles M-tiles [c*8, c*8+8) x all 8 N-tiles.
  const int f = blockIdx.x;
  const int c = f & 7;
  const int l = f >> 3;              // [0,64)
  const int tm0 = (c * 8 + (l >> 3)) * BM;
  const int tn0 = (l & 7) * BN;

  const int wm = (wave & 1) * 64;
  const int wn = (wave >> 1) * 32;

  floatx4 acc[4][2] = {};

  // A reg-staging: 4 chunks/thread, p = t + i*256 over [0,1024).
  // chunk p holds A[row][k0 + ql*8 .. +8) as bf16 at As + p*16,
  // row = p>>3, ql = (p&7) ^ (row&7)  (XOR-chunk swizzle).
  floatx4 areg[4][2];

  auto loadA = [&](int k0) {
#pragma unroll
    for (int i = 0; i < 4; ++i) {
      const int p = t + i * 256;
      const int row = p >> 3;
      const int ql = (p & 7) ^ (row & 7);
      const float* gp = X + (size_t)(tm0 + row) * K + k0 + ql * 8;
      areg[i][0] = *(const floatx4*)gp;
      areg[i][1] = *(const floatx4*)(gp + 4);
    }
  };
  auto writeA = [&](int buf) {
#pragma unroll
    for (int i = 0; i < 4; ++i) {
      const int p = t + i * 256;
      union { short8 v; __hip_bfloat16 h[8]; } u;
#pragma unroll
      for (int j = 0; j < 4; ++j) u.h[j]     = __float2bfloat16(areg[i][0][j]);
#pragma unroll
      for (int j = 0; j < 4; ++j) u.h[4 + j] = __float2bfloat16(areg[i][1][j]);
      *reinterpret_cast<short8*>((char*)&As[buf][0] + p * 16) = u.v;
    }
  };
  auto stageB = [&](int buf, int k0) {
#pragma unroll
    for (int i = 0; i < 2; ++i) {
      const int p = t + i * 256;
      const int row = p >> 3;
      const int ql = (p & 7) ^ (row & 7);
      const __hip_bfloat16* gp = B + (size_t)(tn0 + row) * K + k0 + ql * 8;
      __builtin_amdgcn_global_load_lds(AS_GLOBAL(gp), AS_LDS((char*)&Bs[buf][0] + p * 16), 16, 0, 0);
    }
  };

  // prologue: fill buf 0
  loadA(0);
  stageB(0, 0);
  writeA(0);
  __syncthreads();

  int buf = 0;
  for (int k0 = 0; k0 < K; k0 += BK) {
    const bool next = (k0 + BK < K);
    if (next) { loadA(k0 + BK); stageB(buf ^ 1, k0 + BK); }   // in flight over MFMA

    const char* as = (const char*)&As[buf][0];
    const char* bs = (const char*)&Bs[buf][0];
#pragma unroll
    for (int ks = 0; ks < 2; ++ks) {
      short8 a[4], b[2];
      const int cc = ks * 4 + quad;
#pragma unroll
      for (int i = 0; i < 4; ++i) {
        const int ar = wm + i * 16 + r16;
        a[i] = *reinterpret_cast<const short8*>(as + (ar * 8 + (cc ^ (ar & 7))) * 16);
      }
#pragma unroll
      for (int j = 0; j < 2; ++j) {
        const int br = wn + j * 16 + r16;
        b[j] = *reinterpret_cast<const short8*>(bs + (br * 8 + (cc ^ (br & 7))) * 16);
      }
#pragma unroll
      for (int i = 0; i < 4; ++i)
#pragma unroll
        for (int j = 0; j < 2; ++j)
          acc[i][j] = __builtin_amdgcn_mfma_f32_16x16x32_bf16(a[i], b[j], acc[i][j], 0, 0, 0);
    }

    if (next) writeA(buf ^ 1);   // cvt+ds_write to the OTHER buffer: no race with
                                 // this iteration's readers of buf; made visible
                                 // by the barrier below.
    __syncthreads();             // drains B gld_lds + A ds_writes for buf^1
    buf ^= 1;
  }

#pragma unroll
  for (int i = 0; i < 4; ++i)
#pragma unroll
    for (int j = 0; j < 2; ++j)
#pragma unroll
      for (int r = 0; r < 4; ++r) {
        const int row = tm0 + wm + i * 16 + quad * 4 + r;
        const int col = tn0 + wn + j * 16 + r16;
        C[(size_t)row * N + col] = __float2bfloat16(acc[i][j][r]);
      }
}

// ---------------- GEMM2: Y[M,4096] = H[M,512] @ W2[4096,512]^T + bias ------
// ROUND-0 structure (known-good): BM=128, BN=128, BK=64, single-buffered,
// launch_bounds(256,3) -> 3 blocks/CU (32 KB LDS each). The round-1 dbuf
// variant cut occupancy 3->2 blocks/CU — m132-style regression. Reverted.
__global__ __launch_bounds__(256, 3)
void gemm2_kernel(const __hip_bfloat16* __restrict__ A,
                  const __hip_bfloat16* __restrict__ B,
                  const float* __restrict__ bias,
                  float* __restrict__ C) {
  constexpr int K = S2;        // 512
  constexpr int N = OUT_DIM;   // 4096
  constexpr int BM = 128, BN = 128, BK = 64;

  __shared__ __hip_bfloat16 As[BM * BK];   // 16 KB
  __shared__ __hip_bfloat16 Bs[BN * BK];   // 16 KB

  const int t = threadIdx.x;
  const int wave = t >> 6;
  const int lane = t & 63;
  const int r16 = lane & 15;
  const int quad = lane >> 4;

  // XCD swizzle: 2048 blocks; XCD c handles M-tiles [c*8,c*8+8) x all 32 N-tiles.
  const int f = blockIdx.x;
  const int c = f & 7;
  const int l = f >> 3;              // [0,256)
  const int tm0 = (c * 8 + (l >> 5)) * BM;
  const int tn0 = (l & 31) * BN;

  const int wm = (wave & 1) * 64;
  const int wn = (wave >> 1) * 64;

  floatx4 acc[4][4] = {};

  for (int k0 = 0; k0 < K; k0 += BK) {
#pragma unroll
    for (int i = 0; i < 4; ++i) {
      const int p = t + i * 256;
      const int row = p >> 3;
      const int ql = (p & 7) ^ (row & 7);
      const __hip_bfloat16* gp = A + (size_t)(tm0 + row) * K + k0 + ql * 8;
      __builtin_amdgcn_global_load_lds(AS_GLOBAL(gp), AS_LDS((char*)As + p * 16), 16, 0, 0);
    }
#pragma unroll
    for (int i = 0; i < 4; ++i) {
      const int p = t + i * 256;
      const int row = p >> 3;
      const int ql = (p & 7) ^ (row & 7);
      const __hip_bfloat16* gp = B + (size_t)(tn0 + row) * K + k0 + ql * 8;
      __builtin_amdgcn_global_load_lds(AS_GLOBAL(gp), AS_LDS((char*)Bs + p * 16), 16, 0, 0);
    }
    __syncthreads();

#pragma unroll
    for (int ks = 0; ks < 2; ++ks) {
      short8 a[4], b[4];
      const int cc = ks * 4 + quad;
#pragma unroll
      for (int i = 0; i < 4; ++i) {
        const int ar = wm + i * 16 + r16;
        a[i] = *reinterpret_cast<const short8*>((const char*)As + (ar * 8 + (cc ^ (ar & 7))) * 16);
      }
#pragma unroll
      for (int j = 0; j < 4; ++j) {
        const int br = wn + j * 16 + r16;
        b[j] = *reinterpret_cast<const short8*>((const char*)Bs + (br * 8 + (cc ^ (br & 7))) * 16);
      }
#pragma unroll
      for (int i = 0; i < 4; ++i)
#pragma unroll
        for (int j = 0; j < 4; ++j)
          acc[i][j] = __builtin_amdgcn_mfma_f32_16x16x32_bf16(a[i], b[j], acc[i][j], 0, 0, 0);
    }
    __syncthreads();
  }

  // epilogue: bias + fp32 store
  float bi[4];
#pragma unroll
  for (int j = 0; j < 4; ++j) bi[j] = bias[tn0 + wn + j * 16 + r16];

#pragma unroll
  for (int i = 0; i < 4; ++i)
#pragma unroll
    for (int j = 0; j < 4; ++j)
#pragma unroll
      for (int r = 0; r < 4; ++r) {
        const int row = tm0 + wm + i * 16 + quad * 4 + r;
        const int col = tn0 + wn + j * 16 + r16;
        C[(size_t)row * N + col] = acc[i][j][r] + bi[j];
      }
}

// ---------------- launch ----------------
extern "C" void kernel_launch(void* const* d_in, const int* in_sizes, int n_in,
                              void* d_out, int out_size, void* d_ws, size_t ws_size,
                              hipStream_t stream) {
  const float* x    = (const float*)d_in[0];
  const float* V    = (const float*)d_in[1];
  const float* U    = (const float*)d_in[2];
  const float* v1   = (const float*)d_in[3];
  const float* v2   = (const float*)d_in[4];
  const float* u1   = (const float*)d_in[5];
  const float* u2   = (const float*)d_in[6];
  const float* V_R  = (const float*)d_in[7];
  const float* U_R  = (const float*)d_in[8];
  const float* v1_R = (const float*)d_in[9];
  const float* v2_R = (const float*)d_in[10];
  const float* u1_R = (const float*)d_in[11];
  const float* u2_R = (const float*)d_in[12];
  const float* bias = (const float*)d_in[13];
  float* out = (float*)d_out;

  const int M = in_sizes[0] / IN_DIM;   // 8192

  char* ws = (char*)d_ws;
  __hip_bfloat16* W1 = (__hip_bfloat16*)ws;                                   // 4 MB
  __hip_bfloat16* W2 = (__hip_bfloat16*)(ws + (size_t)4 * 1024 * 1024);       // 4 MB
  __hip_bfloat16* H  = (__hip_bfloat16*)(ws + (size_t)8 * 1024 * 1024);       // M*512*2 = 8 MB

  // prep: W1 (2048 blocks) + W2 (2048 blocks); no x-conversion pass anymore
  prep_kernel<<<4096, 256, 0, stream>>>(
      V, v2, V_R, v2_R, U, u1, v1, u2, U_R, u1_R, v1_R, u2_R, W1, W2);

  // GEMM1: (M/128) x (512/64) = 64 x 8 = 512 blocks, reads fp32 x directly
  gemm1_kernel<<<(M / 128) * (S2 / 64), 256, 0, stream>>>(x, W1, H);

  // GEMM2: (M/128) x (4096/128) = 64 x 32 = 2048 blocks
  gemm2_kernel<<<(M / 128) * (OUT_DIM / 128), 256, 0, stream>>>(H, W2, bias, out);
}

// Round 4
// 346.881 us; speedup vs baseline: 1.0466x; 1.0466x over previous
//
#include <hip/hip_runtime.h>
#include <hip/hip_bf16.h>
#include <stdint.h>
#include <stddef.h>

typedef __attribute__((ext_vector_type(8))) short short8;
typedef __attribute__((ext_vector_type(4))) float floatx4;

#define AS_GLOBAL(p) (const __attribute__((address_space(1))) void*)(p)
#define AS_LDS(p)    (__attribute__((address_space(3))) void*)(p)

// Counted vmcnt waits (T4): leave the newer tile's loads in flight across the
// barrier. "memory" clobber stops the compiler hoisting LDS reads above it.
#define WAIT_VM6() asm volatile("s_waitcnt vmcnt(6)" ::: "memory")
#define WAIT_VM8() asm volatile("s_waitcnt vmcnt(8)" ::: "memory")
#define WAIT_VM0() asm volatile("s_waitcnt vmcnt(0)" ::: "memory")

static constexpr int IN_DIM  = 4096;
static constexpr int OUT_DIM = 4096;
static constexpr int S_DIM   = 256;
static constexpr int S2      = 512;   // both branches concatenated along rank

// ---------------- fused prep: W1, W2, x->bf16 in ONE launch (round-0) ------
__global__ void prep_kernel(const float* __restrict__ V, const float* __restrict__ v2,
                            const float* __restrict__ V_R, const float* __restrict__ v2_R,
                            const float* __restrict__ U, const float* __restrict__ u1,
                            const float* __restrict__ v1, const float* __restrict__ u2,
                            const float* __restrict__ U_R, const float* __restrict__ u1_R,
                            const float* __restrict__ v1_R, const float* __restrict__ u2_R,
                            const float* __restrict__ x,
                            __hip_bfloat16* __restrict__ W1,
                            __hip_bfloat16* __restrict__ W2,
                            __hip_bfloat16* __restrict__ Xb) {
  const int bid = blockIdx.x;
  if (bid < 2048) {
    const int idx4 = (bid * 256 + threadIdx.x) * 4;   // over S2*IN_DIM
    const int i = idx4 & (IN_DIM - 1);
    const int s = idx4 >> 12;
    floatx4 w, sc;
    if (s < S_DIM) {
      w  = *(const floatx4*)(V + s * IN_DIM + i);
      sc = *(const floatx4*)(v2 + i);
    } else {
      w  = *(const floatx4*)(V_R + (s - S_DIM) * IN_DIM + i);
      sc = *(const floatx4*)(v2_R + i);
    }
    union { ushort4 v; __hip_bfloat16 h[4]; } u;
#pragma unroll
    for (int j = 0; j < 4; ++j) {
      const float sg = (w[j] > 0.f) ? 1.f : ((w[j] < 0.f) ? -1.f : 0.f);
      u.h[j] = __float2bfloat16(sg * sc[j]);
    }
    *(ushort4*)((unsigned short*)W1 + idx4) = u.v;
  } else if (bid < 4096) {
    const int idx4 = ((bid - 2048) * 256 + threadIdx.x) * 4;   // over OUT_DIM*S2
    const int s = idx4 & (S2 - 1);
    const int o = idx4 >> 9;
    floatx4 w, scs;
    float sco;
    if (s < S_DIM) {
      w   = *(const floatx4*)(U + o * S_DIM + s);
      sco = u1[o];
      const floatx4 a = *(const floatx4*)(v1 + s);
      const floatx4 b = *(const floatx4*)(u2 + s);
      scs = a * b;
    } else {
      const int ss = s - S_DIM;
      w   = *(const floatx4*)(U_R + o * S_DIM + ss);
      sco = u1_R[o];
      const floatx4 a = *(const floatx4*)(v1_R + ss);
      const floatx4 b = *(const floatx4*)(u2_R + ss);
      scs = a * b;
    }
    union { ushort4 v; __hip_bfloat16 h[4]; } u;
#pragma unroll
    for (int j = 0; j < 4; ++j) {
      const float sg = (w[j] > 0.f) ? 1.f : ((w[j] < 0.f) ? -1.f : 0.f);
      u.h[j] = __float2bfloat16(sg * sco * scs[j]);
    }
    *(ushort4*)((unsigned short*)W2 + idx4) = u.v;
  } else {
    const int idx = (bid - 4096) * 256 + threadIdx.x;   // 8 floats / thread
    const floatx4 f0 = *((const floatx4*)x + idx * 2);
    const floatx4 f1 = *((const floatx4*)x + idx * 2 + 1);
    union { short8 v; __hip_bfloat16 h[8]; } u;
    u.h[0] = __float2bfloat16(f0.x); u.h[1] = __float2bfloat16(f0.y);
    u.h[2] = __float2bfloat16(f0.z); u.h[3] = __float2bfloat16(f0.w);
    u.h[4] = __float2bfloat16(f1.x); u.h[5] = __float2bfloat16(f1.y);
    u.h[6] = __float2bfloat16(f1.z); u.h[7] = __float2bfloat16(f1.w);
    *((short8*)Xb + idx) = u.v;
  }
}

// ---------------- GEMM1: H[M,512] = Xb[M,4096] @ W1[512,4096]^T ----------------
// Round-0 tile config (BM=128, BN=64, BK=64, 256thr, 64x32 wave tiles, 48 KB
// LDS dbuf, grid 512 = 2 blocks/CU) — but the __syncthreads() per K-step is
// replaced by the T3+T4 counted-vmcnt pipeline: tiles staged 2-deep, raw
// s_barrier, and s_waitcnt vmcnt(6) (= the newer tile's 6 loads stay in
// flight across the barrier). r3 counters showed this loop latency-bound
// (MfmaUtil 11%, all pipes <11%): the per-iteration vmcnt(0) drain was the
// bottleneck, not LDS BW. Race-safety: each wave waits its OWN tile-k loads
// (FIFO vmcnt), barrier #1 makes tile-k globally ready; barrier #2 ensures
// all readers of buf are done before it is restaged.
__global__ __launch_bounds__(256, 2)
void gemm1_kernel(const __hip_bfloat16* __restrict__ A,
                  const __hip_bfloat16* __restrict__ B,
                  __hip_bfloat16* __restrict__ C) {
  constexpr int K = IN_DIM;   // 4096
  constexpr int N = S2;       // 512
  constexpr int BM = 128, BN = 64, BK = 64;
  constexpr int NT = K / BK;  // 64 tiles

  __shared__ __hip_bfloat16 As[2][BM * BK];   // 2 x 16 KB
  __shared__ __hip_bfloat16 Bs[2][BN * BK];   // 2 x 8 KB

  const int t = threadIdx.x;
  const int wave = t >> 6;
  const int lane = t & 63;
  const int r16 = lane & 15;
  const int quad = lane >> 4;

  // XCD swizzle: 512 blocks; XCD c handles M-tiles [c*8, c*8+8) x all 8 N-tiles.
  const int f = blockIdx.x;
  const int c = f & 7;
  const int l = f >> 3;              // [0,64)
  const int tm0 = (c * 8 + (l >> 3)) * BM;
  const int tn0 = (l & 7) * BN;

  const int wm = (wave & 1) * 64;
  const int wn = (wave >> 1) * 32;

  floatx4 acc[4][2] = {};

  // 6 vmem ops per thread per tile (4 A + 2 B), FIFO order fixed.
  auto stage = [&](int buf, int k0) {
#pragma unroll
    for (int i = 0; i < 4; ++i) {
      const int p = t + i * 256;
      const int row = p >> 3;
      const int ql = (p & 7) ^ (row & 7);
      const __hip_bfloat16* gp = A + (size_t)(tm0 + row) * K + k0 + ql * 8;
      __builtin_amdgcn_global_load_lds(AS_GLOBAL(gp), AS_LDS((char*)&As[buf][0] + p * 16), 16, 0, 0);
    }
#pragma unroll
    for (int i = 0; i < 2; ++i) {
      const int p = t + i * 256;
      const int row = p >> 3;
      const int ql = (p & 7) ^ (row & 7);
      const __hip_bfloat16* gp = B + (size_t)(tn0 + row) * K + k0 + ql * 8;
      __builtin_amdgcn_global_load_lds(AS_GLOBAL(gp), AS_LDS((char*)&Bs[buf][0] + p * 16), 16, 0, 0);
    }
  };

  stage(0, 0);
  stage(1, BK);        // 12 loads in flight

  for (int ti = 0; ti < NT; ++ti) {
    if (ti < NT - 1) { WAIT_VM6(); } else { WAIT_VM0(); }   // tile ti landed; ti+1 in flight
    __builtin_amdgcn_sched_barrier(0);
    __builtin_amdgcn_s_barrier();                           // tile ti ready for ALL waves

    const int buf = ti & 1;
    const char* as = (const char*)&As[buf][0];
    const char* bs = (const char*)&Bs[buf][0];
#pragma unroll
    for (int ks = 0; ks < 2; ++ks) {
      short8 a[4], b[2];
      const int cc = ks * 4 + quad;
#pragma unroll
      for (int i = 0; i < 4; ++i) {
        const int ar = wm + i * 16 + r16;
        a[i] = *reinterpret_cast<const short8*>(as + (ar * 8 + (cc ^ (ar & 7))) * 16);
      }
#pragma unroll
      for (int j = 0; j < 2; ++j) {
        const int br = wn + j * 16 + r16;
        b[j] = *reinterpret_cast<const short8*>(bs + (br * 8 + (cc ^ (br & 7))) * 16);
      }
#pragma unroll
      for (int i = 0; i < 4; ++i)
#pragma unroll
        for (int j = 0; j < 2; ++j)
          acc[i][j] = __builtin_amdgcn_mfma_f32_16x16x32_bf16(a[i], b[j], acc[i][j], 0, 0, 0);
    }

    __builtin_amdgcn_s_barrier();                           // all readers of buf done
    if (ti + 2 < NT) stage(buf, (ti + 2) * BK);             // restage; stays in flight
  }

#pragma unroll
  for (int i = 0; i < 4; ++i)
#pragma unroll
    for (int j = 0; j < 2; ++j)
#pragma unroll
      for (int r = 0; r < 4; ++r) {
        const int row = tm0 + wm + i * 16 + quad * 4 + r;
        const int col = tn0 + wn + j * 16 + r16;
        C[(size_t)row * N + col] = __float2bfloat16(acc[i][j][r]);
      }
}

// ---------------- GEMM2: Y[M,4096] = H[M,512] @ W2[4096,512]^T + bias ------
// Same counted-vmcnt pipeline (8 loads/thread/tile -> vmcnt(8)). LDS 64 KB
// dbuf -> 2 blocks/CU (was 3 single-buffered): the removed vmcnt(0) drain on
// each of the 8 K-iterations is the bet; r1 showed dbuf-with-full-drain at 2
// blocks/CU loses, counted-dbuf is the version that pays (m218).
__global__ __launch_bounds__(256, 2)
void gemm2_kernel(const __hip_bfloat16* __restrict__ A,
                  const __hip_bfloat16* __restrict__ B,
                  const float* __restrict__ bias,
                  float* __restrict__ C) {
  constexpr int K = S2;        // 512
  constexpr int N = OUT_DIM;   // 4096
  constexpr int BM = 128, BN = 128, BK = 64;
  constexpr int NT = K / BK;   // 8 tiles

  __shared__ __hip_bfloat16 As[2][BM * BK];   // 2 x 16 KB
  __shared__ __hip_bfloat16 Bs[2][BN * BK];   // 2 x 16 KB

  const int t = threadIdx.x;
  const int wave = t >> 6;
  const int lane = t & 63;
  const int r16 = lane & 15;
  const int quad = lane >> 4;

  // XCD swizzle: 2048 blocks; XCD c handles M-tiles [c*8,c*8+8) x all 32 N-tiles.
  const int f = blockIdx.x;
  const int c = f & 7;
  const int l = f >> 3;              // [0,256)
  const int tm0 = (c * 8 + (l >> 5)) * BM;
  const int tn0 = (l & 31) * BN;

  const int wm = (wave & 1) * 64;
  const int wn = (wave >> 1) * 64;

  floatx4 acc[4][4] = {};

  // 8 vmem ops per thread per tile (4 A + 4 B), FIFO order fixed.
  auto stage = [&](int buf, int k0) {
#pragma unroll
    for (int i = 0; i < 4; ++i) {
      const int p = t + i * 256;
      const int row = p >> 3;
      const int ql = (p & 7) ^ (row & 7);
      const __hip_bfloat16* gp = A + (size_t)(tm0 + row) * K + k0 + ql * 8;
      __builtin_amdgcn_global_load_lds(AS_GLOBAL(gp), AS_LDS((char*)&As[buf][0] + p * 16), 16, 0, 0);
    }
#pragma unroll
    for (int i = 0; i < 4; ++i) {
      const int p = t + i * 256;
      const int row = p >> 3;
      const int ql = (p & 7) ^ (row & 7);
      const __hip_bfloat16* gp = B + (size_t)(tn0 + row) * K + k0 + ql * 8;
      __builtin_amdgcn_global_load_lds(AS_GLOBAL(gp), AS_LDS((char*)&Bs[buf][0] + p * 16), 16, 0, 0);
    }
  };

  stage(0, 0);
  stage(1, BK);        // 16 loads in flight

  for (int ti = 0; ti < NT; ++ti) {
    if (ti < NT - 1) { WAIT_VM8(); } else { WAIT_VM0(); }
    __builtin_amdgcn_sched_barrier(0);
    __builtin_amdgcn_s_barrier();

    const int buf = ti & 1;
    const char* as = (const char*)&As[buf][0];
    const char* bs = (const char*)&Bs[buf][0];
#pragma unroll
    for (int ks = 0; ks < 2; ++ks) {
      short8 a[4], b[4];
      const int cc = ks * 4 + quad;
#pragma unroll
      for (int i = 0; i < 4; ++i) {
        const int ar = wm + i * 16 + r16;
        a[i] = *reinterpret_cast<const short8*>(as + (ar * 8 + (cc ^ (ar & 7))) * 16);
      }
#pragma unroll
      for (int j = 0; j < 4; ++j) {
        const int br = wn + j * 16 + r16;
        b[j] = *reinterpret_cast<const short8*>(bs + (br * 8 + (cc ^ (br & 7))) * 16);
      }
#pragma unroll
      for (int i = 0; i < 4; ++i)
#pragma unroll
        for (int j = 0; j < 4; ++j)
          acc[i][j] = __builtin_amdgcn_mfma_f32_16x16x32_bf16(a[i], b[j], acc[i][j], 0, 0, 0);
    }

    __builtin_amdgcn_s_barrier();
    if (ti + 2 < NT) stage(buf, (ti + 2) * BK);
  }

  // epilogue: bias + fp32 store
  float bi[4];
#pragma unroll
  for (int j = 0; j < 4; ++j) bi[j] = bias[tn0 + wn + j * 16 + r16];

#pragma unroll
  for (int i = 0; i < 4; ++i)
#pragma unroll
    for (int j = 0; j < 4; ++j)
#pragma unroll
      for (int r = 0; r < 4; ++r) {
        const int row = tm0 + wm + i * 16 + quad * 4 + r;
        const int col = tn0 + wn + j * 16 + r16;
        C[(size_t)row * N + col] = acc[i][j][r] + bi[j];
      }
}

// ---------------- launch ----------------
extern "C" void kernel_launch(void* const* d_in, const int* in_sizes, int n_in,
                              void* d_out, int out_size, void* d_ws, size_t ws_size,
                              hipStream_t stream) {
  const float* x    = (const float*)d_in[0];
  const float* V    = (const float*)d_in[1];
  const float* U    = (const float*)d_in[2];
  const float* v1   = (const float*)d_in[3];
  const float* v2   = (const float*)d_in[4];
  const float* u1   = (const float*)d_in[5];
  const float* u2   = (const float*)d_in[6];
  const float* V_R  = (const float*)d_in[7];
  const float* U_R  = (const float*)d_in[8];
  const float* v1_R = (const float*)d_in[9];
  const float* v2_R = (const float*)d_in[10];
  const float* u1_R = (const float*)d_in[11];
  const float* u2_R = (const float*)d_in[12];
  const float* bias = (const float*)d_in[13];
  float* out = (float*)d_out;

  const int M = in_sizes[0] / IN_DIM;   // 8192

  char* ws = (char*)d_ws;
  __hip_bfloat16* W1 = (__hip_bfloat16*)ws;                                   // 4 MB
  __hip_bfloat16* W2 = (__hip_bfloat16*)(ws + (size_t)4 * 1024 * 1024);       // 4 MB
  __hip_bfloat16* H  = (__hip_bfloat16*)(ws + (size_t)8 * 1024 * 1024);       // M*512*2 = 8 MB
  __hip_bfloat16* Xb = (__hip_bfloat16*)(ws + (size_t)16 * 1024 * 1024);      // M*4096*2 = 64 MB

  // fused prep: 2048 (W1) + 2048 (W2) + M*IN/(8*256) (cvt) blocks
  const int cvt_blocks = (M * IN_DIM) / (8 * 256);
  prep_kernel<<<4096 + cvt_blocks, 256, 0, stream>>>(
      V, v2, V_R, v2_R, U, u1, v1, u2, U_R, u1_R, v1_R, u2_R, x, W1, W2, Xb);

  // GEMM1: (M/128) x (512/64) = 64 x 8 = 512 blocks, XCD-swizzled in-kernel
  gemm1_kernel<<<(M / 128) * (S2 / 64), 256, 0, stream>>>(Xb, W1, H);

  // GEMM2: (M/128) x (4096/128) = 64 x 32 = 2048 blocks
  gemm2_kernel<<<(M / 128) * (OUT_DIM / 128), 256, 0, stream>>>(H, W2, bias, out);
}